// Round 5
// baseline (61.026 us; speedup 1.0000x reference)
//
#include <hip/hip_runtime.h>
#include <math.h>
#include <float.h>

// Zonotope distance + gradient. One 64-lane wave per point.
// H=48 hyperplanes, V=96 edges.
// R5: H^2 inner loop forced to packed fp32 (v_pk_mul/add — per-half IEEE
// identical to scalar ops); epilogue gradient divide vectorized across
// lanes 0..2 (one v_div sequence instead of three, one coalesced store).
// ALL floating-point op orders match the numpy reference exactly
// (contract(off); no FMA; sub as add-of-negative which is exact).

typedef float f32x4 __attribute__((ext_vector_type(4)));
typedef float f32x2 __attribute__((ext_vector_type(2)));

constexpr int H = 48;
constexpr int V = 96;
constexpr int WPB = 4;          // waves per block
constexpr float ZEPS = 1e-4f;

__device__ __forceinline__ void gload_lds16(const void* g, void* lds) {
  __builtin_amdgcn_global_load_lds(
      (const __attribute__((address_space(1))) void*)g,
      (__attribute__((address_space(3))) void*)lds, 16, 0, 0);
}

__device__ __forceinline__ f32x2 pkmul(f32x2 a, f32x2 b) {
  f32x2 d;
  asm("v_pk_mul_f32 %0, %1, %2" : "=v"(d) : "v"(a), "v"(b));
  return d;
}
__device__ __forceinline__ f32x2 pkadd(f32x2 a, f32x2 b) {
  f32x2 d;
  asm("v_pk_add_f32 %0, %1, %2" : "=v"(d) : "v"(a), "v"(b));
  return d;
}

__global__ __launch_bounds__(256, 8) void zono_dist_kernel(
    const float* __restrict__ point,   // [N,3]
    const float* __restrict__ Ag,      // [N,H,3]
    const float* __restrict__ bg,      // [N,H]
    const float* __restrict__ v1g,     // [N,V,3]
    const float* __restrict__ v2g,     // [N,V,3]
    float* __restrict__ out,           // [N] dist ++ [N,3] grad
    int N)
{
#pragma clang fp contract(off)
  __shared__ __align__(16) float sAb[WPB][192];   // A[48*3] ++ b[48]
  __shared__ __align__(16) float sQx[WPB][48];
  __shared__ __align__(16) float sQy[WPB][48];
  __shared__ __align__(16) float sQz[WPB][48];
  // per wave: v1 = floats [0..287], v2 = [288..575], slop = [576..767]
  __shared__ __align__(16) float sEV[WPB][768];

  const int wave = threadIdx.x >> 6;
  const int lane = threadIdx.x & 63;
  const int n = blockIdx.x * WPB + wave;
  if (n >= N) return;
  const int nu = __builtin_amdgcn_readfirstlane(n);   // uniform -> s_load paths

  // ---- async edge payload -> LDS (in flight under the whole H^2 loop) ----
  {
    const float4* V1f4 = (const float4*)(v1g + (size_t)nu * (V * 3)); // 72 f4
    const float4* V2f4 = (const float4*)(v2g + (size_t)nu * (V * 3)); // 72 f4
    const float4* s1 = V1f4 + lane;                                   // f 0..255
    const float4* s2 = (lane < 8) ? (V1f4 + 64 + lane) : (V2f4 + (lane - 8));
    const float4* s3 = (lane < 16) ? (V2f4 + 56 + lane) : (V2f4 + 71); // clamp->slop
    gload_lds16(s1, &sEV[wave][0]);
    gload_lds16(s2, &sEV[wave][256]);
    gload_lds16(s3, &sEV[wave][512]);
  }

  // ---- point via scalar loads (uniform address) ----
  const float px = point[3 * (size_t)nu + 0];
  const float py = point[3 * (size_t)nu + 1];
  const float pz = point[3 * (size_t)nu + 2];

  // ---- coalesced staging: A (36 float4) + b (12 float4) -> LDS ----
  {
    const float4* Af4 = (const float4*)(Ag + (size_t)nu * (H * 3));
    const float4* Bf4 = (const float4*)(bg + (size_t)nu * H);
    float4* dst = (float4*)sAb[wave];
    if (lane < 36)      dst[lane] = Af4[lane];
    else if (lane < 48) dst[lane] = Bf4[lane - 36];
  }

  // ---- own plane from LDS ----
  float ax = 0.f, ay = 0.f, az = 0.f, bb = 1e30f;  // lanes >=H neutral
  if (lane < H) {
    ax = sAb[wave][3 * lane + 0];
    ay = sAb[wave][3 * lane + 1];
    az = sAb[wave][3 * lane + 2];
    bb = sAb[wave][144 + lane];
  }

  // ---- signed facet offset + projection (exact ref op order) ----
  float apb = -INFINITY;
  float qx = 0.f, qy = 0.f, qz = 0.f;
  if (lane < H) {
    apb = ((ax * px + ay * py) + az * pz) - bb;
    qx = px - apb * ax;
    qy = py - apb * ay;
    qz = pz - apb * az;
    sQx[wave][lane] = qx;
    sQy[wave][lane] = qy;
    sQz[wave][lane] = qz;
  }
  const bool is_neg = (bool)__all(apb <= 0.0f);

  // ---- on-zonotope check, transposed; packed fp32 math ----
  // s = ((ax*q x + ay*qy) + az*qz) + (-bb)  — identical rounding to ref.
  const f32x2 ax2 = {ax, ax}, ay2 = {ay, ay}, az2 = {az, az};
  const f32x2 nbb2 = {-bb, -bb};
  unsigned long long bad = 0;           // bit h set => on_zono[h] false
  const f32x4* Qx4 = (const f32x4*)sQx[wave];
  const f32x4* Qy4 = (const f32x4*)sQy[wave];
  const f32x4* Qz4 = (const f32x4*)sQz[wave];
  #pragma unroll
  for (int g = 0; g < 12; ++g) {
    f32x4 X = Qx4[g], Y = Qy4[g], Z = Qz4[g];   // broadcast reads
    f32x2 xlo = __builtin_shufflevector(X, X, 0, 1);
    f32x2 xhi = __builtin_shufflevector(X, X, 2, 3);
    f32x2 ylo = __builtin_shufflevector(Y, Y, 0, 1);
    f32x2 yhi = __builtin_shufflevector(Y, Y, 2, 3);
    f32x2 zlo = __builtin_shufflevector(Z, Z, 0, 1);
    f32x2 zhi = __builtin_shufflevector(Z, Z, 2, 3);
    f32x2 tlo = pkadd(pkmul(ax2, xlo), pkmul(ay2, ylo));
    tlo = pkadd(tlo, pkmul(az2, zlo));
    tlo = pkadd(tlo, nbb2);
    f32x2 thi = pkadd(pkmul(ax2, xhi), pkmul(ay2, yhi));
    thi = pkadd(thi, pkmul(az2, zhi));
    thi = pkadd(thi, nbb2);
    int h = g * 4;
    unsigned long long b0 = (unsigned long long)(!__all(tlo.x <= ZEPS));
    unsigned long long b1 = (unsigned long long)(!__all(tlo.y <= ZEPS));
    unsigned long long b2 = (unsigned long long)(!__all(thi.x <= ZEPS));
    unsigned long long b3 = (unsigned long long)(!__all(thi.y <= ZEPS));
    bad |= (b0 << h) | (b1 << (h + 1)) | (b2 << (h + 2)) | (b3 << (h + 3));
  }
  const unsigned long long MASK48 = (1ull << H) - 1;
  const bool any_face = ((~bad) & MASK48) != 0;

  // ---- face distance (gated; rare for random data) ----
  float fv = INFINITY; int fi = 0;
  float fgx = 0.f, fgy = 0.f, fgz = 0.f;
  if (any_face) {
    float pv = INFINITY;
    if (lane < H && !((bad >> lane) & 1)) {
      float dx = px - qx, dy = py - qy, dz = pz - qz;   // ref: p - proj
      pv = sqrtf((dx * dx + dy * dy) + dz * dz);
    }
    fv = pv; fi = lane;
    #pragma unroll
    for (int off = 32; off; off >>= 1) {
      float ov = __shfl_xor(fv, off);
      int oi = __shfl_xor(fi, off);
      if (ov < fv || (ov == fv && oi < fi)) { fv = ov; fi = oi; }
    }
    fgx = __shfl(ax, fi); fgy = __shfl(ay, fi); fgz = __shfl(az, fi);
  }

  // ---- inside-zonotope path (gated; rare) ----
  float nv = 0.f;
  float ngx = 0.f, ngy = 0.f, ngz = 0.f;
  if (is_neg) {
    nv = apb; int ni = lane;
    #pragma unroll
    for (int off = 32; off; off >>= 1) {
      float ov = __shfl_xor(nv, off);
      int oi = __shfl_xor(ni, off);
      if (ov > nv || (ov == nv && oi < ni)) { nv = ov; ni = oi; }
    }
    ngx = __shfl(ax, ni); ngy = __shfl(ay, ni); ngz = __shfl(az, ni);
  }

  // ---- drain async edge loads, then edge distances from LDS ----
  asm volatile("s_waitcnt vmcnt(0)" ::: "memory");
  __builtin_amdgcn_sched_barrier(0);

  float bed, bvx, bvy, bvz;
  int bei;
  const float* ev = sEV[wave];
  {
    int e = lane;                                   // round 1: edges 0..63
    float x1 = ev[3 * e + 0], y1 = ev[3 * e + 1], z1 = ev[3 * e + 2];
    float x2 = ev[288 + 3 * e + 0], y2 = ev[288 + 3 * e + 1], z2 = ev[288 + 3 * e + 2];
    float dx = x2 - x1, dy = y2 - y1, dz = z2 - z1;
    float denom = (dx * dx + dy * dy) + dz * dz;
    float wx = px - x1, wy = py - y1, wz = pz - z1;
    float th = ((wx * dx + wy * dy) + wz * dz) / denom;
    float ts = th < 0.0f ? 0.0f : (th > 1.0f ? 1.0f : th);
    float vx = x1 + ts * dx, vy = y1 + ts * dy, vz = z1 + ts * dz;
    float ex = px - vx, ey = py - vy, ez = pz - vz;
    bed = sqrtf((ex * ex + ey * ey) + ez * ez);
    bei = e; bvx = vx; bvy = vy; bvz = vz;
  }
  {
    int e = 64 | (lane & 31);                       // round 2: duplicated, branch-free
    float x1 = ev[3 * e + 0], y1 = ev[3 * e + 1], z1 = ev[3 * e + 2];
    float x2 = ev[288 + 3 * e + 0], y2 = ev[288 + 3 * e + 1], z2 = ev[288 + 3 * e + 2];
    float dx = x2 - x1, dy = y2 - y1, dz = z2 - z1;
    float denom = (dx * dx + dy * dy) + dz * dz;
    float wx = px - x1, wy = py - y1, wz = pz - z1;
    float th = ((wx * dx + wy * dy) + wz * dz) / denom;
    float ts = th < 0.0f ? 0.0f : (th > 1.0f ? 1.0f : th);
    float vx = x1 + ts * dx, vy = y1 + ts * dy, vz = z1 + ts * dz;
    float ex = px - vx, ey = py - vy, ez = pz - vz;
    float ed = sqrtf((ex * ex + ey * ey) + ez * ez);
    if (ed < bed) { bed = ed; bei = e; bvx = vx; bvy = vy; bvz = vz; }
  }
  // value-min butterfly (short dependent chain)
  float m = bed;
  #pragma unroll
  for (int off = 32; off; off >>= 1) {
    float o = __shfl_xor(m, off);
    if (o < m) m = o;
  }
  // index-min among tied lanes (matches argmin first-index tiebreak)
  int sel = (bed == m) ? bei : 0x7FFFFFFF;
  #pragma unroll
  for (int off = 32; off; off >>= 1) {
    int o = __shfl_xor(sel, off);
    if (o < sel) sel = o;
  }
  const int wl = sel & 63;          // lane holding the winning edge's payload
  const float wvx = __shfl(bvx, wl);
  const float wvy = __shfl(bvy, wl);
  const float wvz = __shfl(bvz, wl);

  // ---- combine; gradient divide vectorized over lanes 0..2 ----
  // All selector inputs are wave-uniform here.
  const bool use_edge = (m < fv);
  float dist;
  float gnum, gden = 1.0f, galt;
  {
    const int d = lane;               // component index for lanes 0..2
    // p[d] and wv[d] selected per lane (uniform sources)
    float pd = (d == 0) ? px : (d == 1) ? py : pz;
    float wd = (d == 0) ? wvx : (d == 1) ? wvy : wvz;
    float fd = (d == 0) ? fgx : (d == 1) ? fgy : fgz;
    float nd = (d == 0) ? ngx : (d == 1) ? ngy : ngz;
    if (is_neg) {
      dist = nv;
      gnum = nd; gden = 1.0f; galt = nd;
    } else if (use_edge) {
      dist = m;
      gnum = pd - wd; gden = m; galt = 0.f;
    } else {
      dist = fv;
      gnum = fd; gden = 1.0f; galt = fd;
    }
  }
  float g = gnum / gden;              // one v_div sequence for all 3 components
  if (lane < 3) out[(size_t)N + 3 * (size_t)n + lane] = g;
  if (lane == 0) out[n] = dist;
}

extern "C" void kernel_launch(void* const* d_in, const int* in_sizes, int n_in,
                              void* d_out, int out_size, void* d_ws, size_t ws_size,
                              hipStream_t stream) {
  const float* point = (const float*)d_in[0];
  const float* Ag    = (const float*)d_in[1];
  const float* bg    = (const float*)d_in[2];
  const float* v1g   = (const float*)d_in[3];
  const float* v2g   = (const float*)d_in[4];
  float* out = (float*)d_out;

  const int N = in_sizes[0] / 3;
  const int blocks = (N + WPB - 1) / WPB;
  zono_dist_kernel<<<blocks, WPB * 64, 0, stream>>>(point, Ag, bg, v1g, v2g, out, N);
}